// Round 2
// baseline (969.579 us; speedup 1.0000x reference)
//
#include <hip/hip_runtime.h>

#define IN_DIM 128
#define OUT_DIM 64

static inline size_t align_up(size_t v, size_t a) { return (v + a - 1) & ~(a - 1); }

// ---------- common ----------

// out[n][c] = bias[c]  (only used by the atomic fallback path)
__global__ __launch_bounds__(256) void init_out_kernel(
    float4* __restrict__ out4, const float4* __restrict__ bias4, int n4) {
  int tid = blockIdx.x * blockDim.x + threadIdx.x;
  int stride = gridDim.x * blockDim.x;
  for (int i = tid; i < n4; i += stride)
    out4[i] = bias4[i & 15];  // 64 floats = 16 float4 per node
}

// h = x @ W. lane = output column (OUT_DIM==64==wave size).
// Each lane holds W[:,lane] in 128 VGPRs -> zero per-k LDS traffic.
__global__ __launch_bounds__(256, 2) void gemm_rowwave(
    const float* __restrict__ x, const float* __restrict__ w,
    float* __restrict__ h, int nrows) {
  const int lane = threadIdx.x & 63;
  const int wid = blockIdx.x * (blockDim.x >> 6) + (threadIdx.x >> 6);
  const int nw = gridDim.x * (blockDim.x >> 6);

  float wreg[IN_DIM];
#pragma unroll
  for (int k = 0; k < IN_DIM; ++k) wreg[k] = w[k * OUT_DIM + lane];

  for (int row = wid; row < nrows; row += nw) {
    const float4* xr = reinterpret_cast<const float4*>(x + (size_t)row * IN_DIM);
    float acc = 0.f;
#pragma unroll
    for (int jj = 0; jj < 4; ++jj) {
      float4 xv[8];
#pragma unroll
      for (int j = 0; j < 8; ++j) xv[j] = xr[jj * 8 + j];
#pragma unroll
      for (int j = 0; j < 8; ++j) {
        const int k = (jj * 8 + j) * 4;
        acc += xv[j].x * wreg[k + 0];
        acc += xv[j].y * wreg[k + 1];
        acc += xv[j].z * wreg[k + 2];
        acc += xv[j].w * wreg[k + 3];
      }
    }
    h[(size_t)row * OUT_DIM + lane] = acc;
  }
}

// ---------- CSR build ----------

__global__ __launch_bounds__(256) void zero_i32(int* __restrict__ p, int n) {
  int tid = blockIdx.x * blockDim.x + threadIdx.x;
  int stride = gridDim.x * blockDim.x;
  for (int i = tid; i < n; i += stride) p[i] = 0;
}

__global__ __launch_bounds__(256) void hist_kernel(
    const int* __restrict__ dst, int nedges, int* __restrict__ counts) {
  int tid = blockIdx.x * blockDim.x + threadIdx.x;
  int stride = gridDim.x * blockDim.x;
  for (int e = tid; e < nedges; e += stride) atomicAdd(&counts[dst[e]], 1);
}

// Block-local exclusive scan (1024 elems/block), emits block sums.
__global__ __launch_bounds__(1024) void scan_block(
    const int* __restrict__ counts, int n, int* __restrict__ offsets,
    int* __restrict__ bsums) {
  __shared__ int buf[1024];
  int gid = blockIdx.x * 1024 + threadIdx.x;
  int v = (gid < n) ? counts[gid] : 0;
  buf[threadIdx.x] = v;
  __syncthreads();
  for (int d = 1; d < 1024; d <<= 1) {
    int t = (threadIdx.x >= d) ? buf[threadIdx.x - d] : 0;
    __syncthreads();
    buf[threadIdx.x] += t;
    __syncthreads();
  }
  if (gid < n) offsets[gid] = buf[threadIdx.x] - v;  // exclusive
  if (threadIdx.x == 1023) bsums[blockIdx.x] = buf[1023];
}

__global__ void scan_bsums(int* __restrict__ bsums, int nb) {
  if (threadIdx.x == 0 && blockIdx.x == 0) {
    int run = 0;
    for (int i = 0; i < nb; ++i) { int v = bsums[i]; bsums[i] = run; run += v; }
  }
}

__global__ __launch_bounds__(256) void add_bsums(
    int* __restrict__ offsets, const int* __restrict__ bsums, int n,
    int* __restrict__ cursor, int nnodes) {
  int tid = blockIdx.x * blockDim.x + threadIdx.x;
  int stride = gridDim.x * blockDim.x;
  for (int i = tid; i < n; i += stride) {
    int o = offsets[i] + bsums[i >> 10];
    offsets[i] = o;
    if (i < nnodes) cursor[i] = o;
  }
}

__global__ __launch_bounds__(256) void fill_kernel(
    const int* __restrict__ ei, const float* __restrict__ ew, int nedges,
    int* __restrict__ cursor, int* __restrict__ csr_src,
    float* __restrict__ csr_w) {
  int tid = blockIdx.x * blockDim.x + threadIdx.x;
  int stride = gridDim.x * blockDim.x;
  for (int e = tid; e < nedges; e += stride) {
    int d = ei[e];
    int s = ei[nedges + e];
    int p = atomicAdd(&cursor[d], 1);
    csr_src[p] = s;
    csr_w[p] = ew[e];
  }
}

// One wave per dst node; lane = output channel. Edge metadata loaded 64 at a
// time and broadcast via __shfl; per edge the wave reads h[src][0..63]
// coalesced (256 B, L3-resident). Zero atomics; bias fused into the store.
__global__ __launch_bounds__(256) void gather_kernel(
    const int* __restrict__ offsets, const int* __restrict__ csr_src,
    const float* __restrict__ csr_w, const float* __restrict__ h,
    const float* __restrict__ bias, float* __restrict__ out, int nnodes) {
  const int lane = threadIdx.x & 63;
  const int wid = blockIdx.x * (blockDim.x >> 6) + (threadIdx.x >> 6);
  const int nw = gridDim.x * (blockDim.x >> 6);
  const float b = bias[lane];

  for (int node = wid; node < nnodes; node += nw) {
    int beg = offsets[node];
    int end = offsets[node + 1];
    float acc = 0.f;
    for (int eo = beg; eo < end; eo += 64) {
      int cnt = min(64, end - eo);
      int ms = (lane < cnt) ? csr_src[eo + lane] : 0;
      float mw = (lane < cnt) ? csr_w[eo + lane] : 0.f;
      for (int j = 0; j < cnt; ++j) {
        int s = __shfl(ms, j);
        float wv = __shfl(mw, j);
        acc += wv * h[(size_t)s * OUT_DIM + lane];
      }
    }
    out[(size_t)node * OUT_DIM + lane] = acc + b;
  }
}

// ---------- atomic fallback (if ws too small for CSR) ----------

__global__ __launch_bounds__(256) void scatter_kernel(
    const int* __restrict__ ei, const float* __restrict__ ew,
    const float* __restrict__ h, float* __restrict__ out, int nedges) {
  int tid = blockIdx.x * blockDim.x + threadIdx.x;
  int stride = gridDim.x * blockDim.x;
  int ntasks = nedges * 16;
  for (int task = tid; task < ntasks; task += stride) {
    int e = task >> 4;
    int sub = task & 15;
    int dst = ei[e];
    int src = ei[nedges + e];
    float wv = ew[e];
    const float4 hv =
        *reinterpret_cast<const float4*>(h + (size_t)src * OUT_DIM + sub * 4);
    float* op = out + (size_t)dst * OUT_DIM + sub * 4;
    atomicAdd(op + 0, wv * hv.x);
    atomicAdd(op + 1, wv * hv.y);
    atomicAdd(op + 2, wv * hv.z);
    atomicAdd(op + 3, wv * hv.w);
  }
}

extern "C" void kernel_launch(void* const* d_in, const int* in_sizes, int n_in,
                              void* d_out, int out_size, void* d_ws, size_t ws_size,
                              hipStream_t stream) {
  const float* x    = (const float*)d_in[0];
  const int*   ei   = (const int*)d_in[1];    // [2, E]: row0 = dst, row1 = src
  const float* ew   = (const float*)d_in[2];
  const float* w    = (const float*)d_in[3];
  const float* bias = (const float*)d_in[4];
  float* out = (float*)d_out;

  const int nrows  = in_sizes[0] / IN_DIM;  // 100000
  const int nedges = in_sizes[2];           // 1600000
  const int nscan  = nrows + 1;
  const int nblk   = (nscan + 1023) / 1024;

  // ws layout
  char* ws = (char*)d_ws;
  size_t o = 0;
  float* h = (float*)(ws + o);           o += align_up((size_t)nrows * OUT_DIM * 4, 512);
  int* counts  = (int*)(ws + o);         o += align_up((size_t)nscan * 4, 512);
  int* offsets = (int*)(ws + o);         o += align_up((size_t)nscan * 4, 512);
  int* cursor  = (int*)(ws + o);         o += align_up((size_t)nrows * 4, 512);
  int* bsums   = (int*)(ws + o);         o += align_up((size_t)nblk * 4, 512);
  int* csr_src = (int*)(ws + o);         o += align_up((size_t)nedges * 4, 512);
  float* csr_w = (float*)(ws + o);       o += align_up((size_t)nedges * 4, 512);
  const bool csr_ok = (o <= ws_size);

  hipLaunchKernelGGL(gemm_rowwave, dim3(2048), dim3(256), 0, stream,
                     x, w, h, nrows);

  if (csr_ok) {
    hipLaunchKernelGGL(zero_i32, dim3(128), dim3(256), 0, stream, counts, nscan);
    hipLaunchKernelGGL(hist_kernel, dim3(2048), dim3(256), 0, stream,
                       ei, nedges, counts);
    hipLaunchKernelGGL(scan_block, dim3(nblk), dim3(1024), 0, stream,
                       counts, nscan, offsets, bsums);
    hipLaunchKernelGGL(scan_bsums, dim3(1), dim3(64), 0, stream, bsums, nblk);
    hipLaunchKernelGGL(add_bsums, dim3(128), dim3(256), 0, stream,
                       offsets, bsums, nscan, cursor, nrows);
    hipLaunchKernelGGL(fill_kernel, dim3(2048), dim3(256), 0, stream,
                       ei, ew, nedges, cursor, csr_src, csr_w);
    hipLaunchKernelGGL(gather_kernel, dim3(4096), dim3(256), 0, stream,
                       offsets, csr_src, csr_w, h, bias, out, nrows);
  } else {
    hipLaunchKernelGGL(init_out_kernel, dim3(2048), dim3(256), 0, stream,
                       (float4*)out, (const float4*)bias, out_size / 4);
    hipLaunchKernelGGL(scatter_kernel, dim3(8192), dim3(256), 0, stream,
                       ei, ew, h, out, nedges);
  }
}

// Round 4
// 419.300 us; speedup vs baseline: 2.3124x; 2.3124x over previous
//
#include <hip/hip_runtime.h>

#define IN_DIM 128
#define OUT_DIM 64
#define PADF 36  // LDS row stride in floats: 144 B, 16B-aligned, non-pow2 banks

static inline size_t align_up(size_t v, size_t a) { return (v + a - 1) & ~(a - 1); }

// ---------- GEMM: h = x @ W ----------
// 1 wave/block, lane = row. acc[64] in VGPRs (static idx). x tile staged in
// LDS; W read at wave-uniform addresses -> s_load + v_fmac with SGPR operand.
__global__ __launch_bounds__(64, 2) void gemm_rowthread(
    const float* __restrict__ x, const float* __restrict__ w,
    float* __restrict__ h, int nrows) {
  __shared__ float xt[64 * PADF];
  const int lane = threadIdx.x;
  const int rb = blockIdx.x * 64;

  float acc[OUT_DIM];
#pragma unroll
  for (int c = 0; c < OUT_DIM; ++c) acc[c] = 0.f;

  const int r = lane >> 3;          // 0..7
  const int kq = (lane & 7) << 2;   // 0,4,..,28

#pragma unroll 1
  for (int kc = 0; kc < IN_DIM; kc += 32) {
    // stage x[rb..rb+63][kc..kc+31] (64 rows x 32 floats), coalesced
#pragma unroll
    for (int p = 0; p < 8; ++p) {
      int row = rb + r + p * 8;
      float4 v = (row < nrows)
                     ? *reinterpret_cast<const float4*>(x + (size_t)row * IN_DIM + kc + kq)
                     : make_float4(0.f, 0.f, 0.f, 0.f);
      *reinterpret_cast<float4*>(&xt[(r + p * 8) * PADF + kq]) = v;
    }
    __syncthreads();
#pragma unroll
    for (int cb = 0; cb < 4; ++cb) {  // 4 col-blocks of 16 -> bounded SGPR set
#pragma unroll
      for (int k4 = 0; k4 < 32; k4 += 4) {
        float4 xv = *reinterpret_cast<const float4*>(&xt[lane * PADF + k4]);
#pragma unroll
        for (int kk = 0; kk < 4; ++kk) {
          float xs = (&xv.x)[kk];
          const float* wk = w + (size_t)(kc + k4 + kk) * OUT_DIM + cb * 16;
#pragma unroll
          for (int c = 0; c < 16; ++c)
            acc[cb * 16 + c] = fmaf(xs, wk[c], acc[cb * 16 + c]);
        }
      }
    }
    __syncthreads();
  }

  int row = rb + lane;
  if (row < nrows) {
    float4* hp = reinterpret_cast<float4*>(h + (size_t)row * OUT_DIM);
#pragma unroll
    for (int c4 = 0; c4 < 16; ++c4)
      hp[c4] = make_float4(acc[c4 * 4], acc[c4 * 4 + 1], acc[c4 * 4 + 2], acc[c4 * 4 + 3]);
  }
}

// ---------- CSR build ----------

__global__ __launch_bounds__(256) void zero_i32(int* __restrict__ p, int n) {
  int tid = blockIdx.x * blockDim.x + threadIdx.x;
  int stride = gridDim.x * blockDim.x;
  for (int i = tid; i < n; i += stride) p[i] = 0;
}

__global__ __launch_bounds__(256) void hist_kernel(
    const int* __restrict__ dst, int nedges, int* __restrict__ counts) {
  int tid = blockIdx.x * blockDim.x + threadIdx.x;
  int stride = gridDim.x * blockDim.x;
  for (int e = tid; e < nedges; e += stride) atomicAdd(&counts[dst[e]], 1);
}

__global__ __launch_bounds__(1024) void scan_block(
    const int* __restrict__ counts, int n, int* __restrict__ offsets,
    int* __restrict__ bsums) {
  __shared__ int buf[1024];
  int gid = blockIdx.x * 1024 + threadIdx.x;
  int v = (gid < n) ? counts[gid] : 0;
  buf[threadIdx.x] = v;
  __syncthreads();
  for (int d = 1; d < 1024; d <<= 1) {
    int t = (threadIdx.x >= d) ? buf[threadIdx.x - d] : 0;
    __syncthreads();
    buf[threadIdx.x] += t;
    __syncthreads();
  }
  if (gid < n) offsets[gid] = buf[threadIdx.x] - v;  // exclusive
  if (threadIdx.x == 1023) bsums[blockIdx.x] = buf[1023];
}

__global__ void scan_bsums(int* __restrict__ bsums, int nb) {
  if (threadIdx.x == 0 && blockIdx.x == 0) {
    int run = 0;
    for (int i = 0; i < nb; ++i) { int v = bsums[i]; bsums[i] = run; run += v; }
  }
}

__global__ __launch_bounds__(256) void add_bsums(
    int* __restrict__ offsets, const int* __restrict__ bsums, int n,
    int* __restrict__ cursor, int nnodes) {
  int tid = blockIdx.x * blockDim.x + threadIdx.x;
  int stride = gridDim.x * blockDim.x;
  for (int i = tid; i < n; i += stride) {
    int o = offsets[i] + bsums[i >> 10];
    offsets[i] = o;
    if (i < nnodes) cursor[i] = o;
  }
}

__global__ __launch_bounds__(256) void fill_kernel(
    const int* __restrict__ ei, const float* __restrict__ ew, int nedges,
    int* __restrict__ cursor, int* __restrict__ csr_src,
    float* __restrict__ csr_w) {
  int tid = blockIdx.x * blockDim.x + threadIdx.x;
  int stride = gridDim.x * blockDim.x;
  for (int e = tid; e < nedges; e += stride) {
    int d = ei[e];
    int s = ei[nedges + e];
    int p = atomicAdd(&cursor[d], 1);
    csr_src[p] = s;
    csr_w[p] = ew[e];
  }
}

// ---------- gather: out[dst] = bias + sum_e w_e * h[src_e] ----------
// One wave per node; lane = channel. 4 edges in flight per step (independent
// loads) to cover L2/L3 latency. Zero atomics.
__global__ __launch_bounds__(256) void gather_kernel(
    const int* __restrict__ offsets, const int* __restrict__ csr_src,
    const float* __restrict__ csr_w, const float* __restrict__ h,
    const float* __restrict__ bias, float* __restrict__ out, int nnodes) {
  const int lane = threadIdx.x & 63;
  const int wid = blockIdx.x * (blockDim.x >> 6) + (threadIdx.x >> 6);
  const int nw = gridDim.x * (blockDim.x >> 6);
  const float b = bias[lane];

  for (int node = wid; node < nnodes; node += nw) {
    int beg = offsets[node];
    int end = offsets[node + 1];
    float acc = 0.f;
    for (int eo = beg; eo < end; eo += 64) {
      int cnt = min(64, end - eo);
      int ms = (lane < cnt) ? csr_src[eo + lane] : 0;
      float mw = (lane < cnt) ? csr_w[eo + lane] : 0.f;
      int j = 0;
      for (; j + 4 <= cnt; j += 4) {
        int s0 = __shfl(ms, j + 0), s1 = __shfl(ms, j + 1);
        int s2 = __shfl(ms, j + 2), s3 = __shfl(ms, j + 3);
        float w0 = __shfl(mw, j + 0), w1 = __shfl(mw, j + 1);
        float w2 = __shfl(mw, j + 2), w3 = __shfl(mw, j + 3);
        float h0 = h[(size_t)s0 * OUT_DIM + lane];
        float h1 = h[(size_t)s1 * OUT_DIM + lane];
        float h2 = h[(size_t)s2 * OUT_DIM + lane];
        float h3 = h[(size_t)s3 * OUT_DIM + lane];
        acc = fmaf(w0, h0, acc);
        acc = fmaf(w1, h1, acc);
        acc = fmaf(w2, h2, acc);
        acc = fmaf(w3, h3, acc);
      }
      for (; j < cnt; ++j) {
        int s = __shfl(ms, j);
        float wv = __shfl(mw, j);
        acc = fmaf(wv, h[(size_t)s * OUT_DIM + lane], acc);
      }
    }
    out[(size_t)node * OUT_DIM + lane] = acc + b;
  }
}

extern "C" void kernel_launch(void* const* d_in, const int* in_sizes, int n_in,
                              void* d_out, int out_size, void* d_ws, size_t ws_size,
                              hipStream_t stream) {
  const float* x    = (const float*)d_in[0];
  const int*   ei   = (const int*)d_in[1];    // [2, E]: row0 = dst, row1 = src
  const float* ew   = (const float*)d_in[2];
  const float* w    = (const float*)d_in[3];
  const float* bias = (const float*)d_in[4];
  float* out = (float*)d_out;

  const int nrows  = in_sizes[0] / IN_DIM;  // 100000
  const int nedges = in_sizes[2];           // 1600000
  const int nscan  = nrows + 1;
  const int nblk   = (nscan + 1023) / 1024;

  // ws layout
  char* ws = (char*)d_ws;
  size_t o = 0;
  float* h = (float*)(ws + o);           o += align_up((size_t)nrows * OUT_DIM * 4, 512);
  int* counts  = (int*)(ws + o);         o += align_up((size_t)nscan * 4, 512);
  int* offsets = (int*)(ws + o);         o += align_up((size_t)nscan * 4, 512);
  int* cursor  = (int*)(ws + o);         o += align_up((size_t)nrows * 4, 512);
  int* bsums   = (int*)(ws + o);         o += align_up((size_t)nblk * 4, 512);
  int* csr_src = (int*)(ws + o);         o += align_up((size_t)nedges * 4, 512);
  float* csr_w = (float*)(ws + o);       o += align_up((size_t)nedges * 4, 512);

  hipLaunchKernelGGL(gemm_rowthread, dim3((nrows + 63) / 64), dim3(64), 0, stream,
                     x, w, h, nrows);
  hipLaunchKernelGGL(zero_i32, dim3(128), dim3(256), 0, stream, counts, nscan);
  hipLaunchKernelGGL(hist_kernel, dim3(2048), dim3(256), 0, stream,
                     ei, nedges, counts);
  hipLaunchKernelGGL(scan_block, dim3(nblk), dim3(1024), 0, stream,
                     counts, nscan, offsets, bsums);
  hipLaunchKernelGGL(scan_bsums, dim3(1), dim3(64), 0, stream, bsums, nblk);
  hipLaunchKernelGGL(add_bsums, dim3(128), dim3(256), 0, stream,
                     offsets, bsums, nscan, cursor, nrows);
  hipLaunchKernelGGL(fill_kernel, dim3(2048), dim3(256), 0, stream,
                     ei, ew, nedges, cursor, csr_src, csr_w);
  hipLaunchKernelGGL(gather_kernel, dim3(4096), dim3(256), 0, stream,
                     offsets, csr_src, csr_w, h, bias, out, nrows);
}

// Round 5
// 391.592 us; speedup vs baseline: 2.4760x; 1.0708x over previous
//
#include <hip/hip_runtime.h>

#define IN_DIM 128
#define OUT_DIM 64
#define PADF 36  // LDS row stride in floats: 144 B, 16B-aligned, non-pow2 banks

static inline size_t align_up(size_t v, size_t a) { return (v + a - 1) & ~(a - 1); }

// ---------- GEMM: h = x @ W ----------
// 1 wave/block, lane = row. acc[64] in VGPRs (static idx). x tile staged in
// LDS; W read at wave-uniform addresses -> s_load + v_fmac with SGPR operand.
__global__ __launch_bounds__(64, 2) void gemm_rowthread(
    const float* __restrict__ x, const float* __restrict__ w,
    float* __restrict__ h, int nrows) {
  __shared__ float xt[64 * PADF];
  const int lane = threadIdx.x;
  const int rb = blockIdx.x * 64;

  float acc[OUT_DIM];
#pragma unroll
  for (int c = 0; c < OUT_DIM; ++c) acc[c] = 0.f;

  const int r = lane >> 3;          // 0..7
  const int kq = (lane & 7) << 2;   // 0,4,..,28

#pragma unroll 1
  for (int kc = 0; kc < IN_DIM; kc += 32) {
#pragma unroll
    for (int p = 0; p < 8; ++p) {
      int row = rb + r + p * 8;
      float4 v = (row < nrows)
                     ? *reinterpret_cast<const float4*>(x + (size_t)row * IN_DIM + kc + kq)
                     : make_float4(0.f, 0.f, 0.f, 0.f);
      *reinterpret_cast<float4*>(&xt[(r + p * 8) * PADF + kq]) = v;
    }
    __syncthreads();
#pragma unroll
    for (int cb = 0; cb < 4; ++cb) {  // 4 col-blocks of 16 -> bounded SGPR set
#pragma unroll
      for (int k4 = 0; k4 < 32; k4 += 4) {
        float4 xv = *reinterpret_cast<const float4*>(&xt[lane * PADF + k4]);
#pragma unroll
        for (int kk = 0; kk < 4; ++kk) {
          float xs = (&xv.x)[kk];
          const float* wk = w + (size_t)(kc + k4 + kk) * OUT_DIM + cb * 16;
#pragma unroll
          for (int c = 0; c < 16; ++c)
            acc[cb * 16 + c] = fmaf(xs, wk[c], acc[cb * 16 + c]);
        }
      }
    }
    __syncthreads();
  }

  int row = rb + lane;
  if (row < nrows) {
    float4* hp = reinterpret_cast<float4*>(h + (size_t)row * OUT_DIM);
#pragma unroll
    for (int c4 = 0; c4 < 16; ++c4)
      hp[c4] = make_float4(acc[c4 * 4], acc[c4 * 4 + 1], acc[c4 * 4 + 2], acc[c4 * 4 + 3]);
  }
}

// ---------- CSR build ----------

__global__ __launch_bounds__(256) void zero_i32(int* __restrict__ p, int n) {
  int tid = blockIdx.x * blockDim.x + threadIdx.x;
  int stride = gridDim.x * blockDim.x;
  for (int i = tid; i < n; i += stride) p[i] = 0;
}

__global__ __launch_bounds__(256) void hist_kernel(
    const int* __restrict__ dst, int nedges, int* __restrict__ counts) {
  int tid = blockIdx.x * blockDim.x + threadIdx.x;
  int stride = gridDim.x * blockDim.x;
  for (int e = tid; e < nedges; e += stride) atomicAdd(&counts[dst[e]], 1);
}

__global__ __launch_bounds__(1024) void scan_block(
    const int* __restrict__ counts, int n, int* __restrict__ offsets,
    int* __restrict__ bsums) {
  __shared__ int buf[1024];
  int gid = blockIdx.x * 1024 + threadIdx.x;
  int v = (gid < n) ? counts[gid] : 0;
  buf[threadIdx.x] = v;
  __syncthreads();
  for (int d = 1; d < 1024; d <<= 1) {
    int t = (threadIdx.x >= d) ? buf[threadIdx.x - d] : 0;
    __syncthreads();
    buf[threadIdx.x] += t;
    __syncthreads();
  }
  if (gid < n) offsets[gid] = buf[threadIdx.x] - v;  // exclusive
  if (threadIdx.x == 1023) bsums[blockIdx.x] = buf[1023];
}

__global__ void scan_bsums(int* __restrict__ bsums, int nb) {
  if (threadIdx.x == 0 && blockIdx.x == 0) {
    int run = 0;
    for (int i = 0; i < nb; ++i) { int v = bsums[i]; bsums[i] = run; run += v; }
  }
}

__global__ __launch_bounds__(256) void add_bsums(
    int* __restrict__ offsets, const int* __restrict__ bsums, int n,
    int* __restrict__ cursor, int nnodes) {
  int tid = blockIdx.x * blockDim.x + threadIdx.x;
  int stride = gridDim.x * blockDim.x;
  for (int i = tid; i < n; i += stride) {
    int o = offsets[i] + bsums[i >> 10];
    offsets[i] = o;
    if (i < nnodes) cursor[i] = o;
  }
}

// XCD-range-partitioned fill: blocks with blockIdx%8==r take only edges whose
// dst is in range r (1/8 of nodes). With default round-robin block->XCD
// mapping, each CSR output region is written by ONE XCD -> its L2 write-
// combines full 64B lines (round-4 counters: 154 MB writebacks for 12.8 MB
// payload without this). (src,w) packed in int2: one 8B store per edge.
// If the XCD mapping differs, correctness is unaffected.
__global__ __launch_bounds__(256) void fill_part_kernel(
    const int* __restrict__ ei, const float* __restrict__ ew, int nedges,
    int* __restrict__ cursor, int2* __restrict__ csr, int nnodes) {
  const int range = blockIdx.x & 7;
  const int ngroups = gridDim.x >> 3;
  const int group = blockIdx.x >> 3;
  const int lo = (int)((size_t)range * nnodes / 8);
  const int hi = (int)((size_t)(range + 1) * nnodes / 8);
  int tid = group * blockDim.x + threadIdx.x;
  int stride = ngroups * blockDim.x;
  for (int e = tid; e < nedges; e += stride) {
    int d = ei[e];
    if (d >= lo && d < hi) {
      int s = ei[nedges + e];
      float wv = ew[e];
      int p = atomicAdd(&cursor[d], 1);
      csr[p] = make_int2(s, __float_as_int(wv));
    }
  }
}

// ---------- gather: out[dst] = bias + sum_e w_e * h[src_e] ----------
// One wave per node; lane = channel. Edge metadata: one coalesced int2 per
// lane, broadcast via shfl. ILP-8, fully predicated (lanes past cnt carry
// w=0 -> read h[0] row, L1-hot, contribute 0) so no serial tail at avg
// degree 16. Zero atomics; bias fused.
__global__ __launch_bounds__(256) void gather_kernel(
    const int* __restrict__ offsets, const int2* __restrict__ csr,
    const float* __restrict__ h, const float* __restrict__ bias,
    float* __restrict__ out, int nnodes) {
  const int lane = threadIdx.x & 63;
  const int wid = blockIdx.x * (blockDim.x >> 6) + (threadIdx.x >> 6);
  const int nw = gridDim.x * (blockDim.x >> 6);
  const float b = bias[lane];

  for (int node = wid; node < nnodes; node += nw) {
    int beg = offsets[node];
    int end = offsets[node + 1];
    float acc = 0.f;
    for (int eo = beg; eo < end; eo += 64) {
      int cnt = min(64, end - eo);
      int2 me = (lane < cnt) ? csr[eo + lane] : make_int2(0, 0);
      int ms = me.x;
      float mw = __int_as_float(me.y);
      for (int j = 0; j < cnt; j += 8) {
        int s0 = __shfl(ms, j + 0), s1 = __shfl(ms, j + 1);
        int s2 = __shfl(ms, j + 2), s3 = __shfl(ms, j + 3);
        int s4 = __shfl(ms, j + 4), s5 = __shfl(ms, j + 5);
        int s6 = __shfl(ms, j + 6), s7 = __shfl(ms, j + 7);
        float w0 = __shfl(mw, j + 0), w1 = __shfl(mw, j + 1);
        float w2 = __shfl(mw, j + 2), w3 = __shfl(mw, j + 3);
        float w4 = __shfl(mw, j + 4), w5 = __shfl(mw, j + 5);
        float w6 = __shfl(mw, j + 6), w7 = __shfl(mw, j + 7);
        float h0 = h[(size_t)s0 * OUT_DIM + lane];
        float h1 = h[(size_t)s1 * OUT_DIM + lane];
        float h2 = h[(size_t)s2 * OUT_DIM + lane];
        float h3 = h[(size_t)s3 * OUT_DIM + lane];
        float h4 = h[(size_t)s4 * OUT_DIM + lane];
        float h5 = h[(size_t)s5 * OUT_DIM + lane];
        float h6 = h[(size_t)s6 * OUT_DIM + lane];
        float h7 = h[(size_t)s7 * OUT_DIM + lane];
        acc = fmaf(w0, h0, acc);
        acc = fmaf(w1, h1, acc);
        acc = fmaf(w2, h2, acc);
        acc = fmaf(w3, h3, acc);
        acc = fmaf(w4, h4, acc);
        acc = fmaf(w5, h5, acc);
        acc = fmaf(w6, h6, acc);
        acc = fmaf(w7, h7, acc);
      }
    }
    out[(size_t)node * OUT_DIM + lane] = acc + b;
  }
}

extern "C" void kernel_launch(void* const* d_in, const int* in_sizes, int n_in,
                              void* d_out, int out_size, void* d_ws, size_t ws_size,
                              hipStream_t stream) {
  const float* x    = (const float*)d_in[0];
  const int*   ei   = (const int*)d_in[1];    // [2, E]: row0 = dst, row1 = src
  const float* ew   = (const float*)d_in[2];
  const float* w    = (const float*)d_in[3];
  const float* bias = (const float*)d_in[4];
  float* out = (float*)d_out;

  const int nrows  = in_sizes[0] / IN_DIM;  // 100000
  const int nedges = in_sizes[2];           // 1600000
  const int nscan  = nrows + 1;
  const int nblk   = (nscan + 1023) / 1024;

  // ws layout
  char* ws = (char*)d_ws;
  size_t o = 0;
  float* h = (float*)(ws + o);           o += align_up((size_t)nrows * OUT_DIM * 4, 512);
  int* counts  = (int*)(ws + o);         o += align_up((size_t)nscan * 4, 512);
  int* offsets = (int*)(ws + o);         o += align_up((size_t)nscan * 4, 512);
  int* cursor  = (int*)(ws + o);         o += align_up((size_t)nrows * 4, 512);
  int* bsums   = (int*)(ws + o);         o += align_up((size_t)nblk * 4, 512);
  int2* csr    = (int2*)(ws + o);        o += align_up((size_t)nedges * 8, 512);

  hipLaunchKernelGGL(gemm_rowthread, dim3((nrows + 63) / 64), dim3(64), 0, stream,
                     x, w, h, nrows);
  hipLaunchKernelGGL(zero_i32, dim3(128), dim3(256), 0, stream, counts, nscan);
  hipLaunchKernelGGL(hist_kernel, dim3(2048), dim3(256), 0, stream,
                     ei, nedges, counts);
  hipLaunchKernelGGL(scan_block, dim3(nblk), dim3(1024), 0, stream,
                     counts, nscan, offsets, bsums);
  hipLaunchKernelGGL(scan_bsums, dim3(1), dim3(64), 0, stream, bsums, nblk);
  hipLaunchKernelGGL(add_bsums, dim3(128), dim3(256), 0, stream,
                     offsets, bsums, nscan, cursor, nrows);
  hipLaunchKernelGGL(fill_part_kernel, dim3(2048), dim3(256), 0, stream,
                     ei, ew, nedges, cursor, csr, nrows);
  hipLaunchKernelGGL(gather_kernel, dim3(4096), dim3(256), 0, stream,
                     offsets, csr, h, bias, out, nrows);
}

// Round 6
// 335.371 us; speedup vs baseline: 2.8911x; 1.1676x over previous
//
#include <hip/hip_runtime.h>

#define IN_DIM 128
#define OUT_DIM 64
#define PADF 36  // LDS row stride in floats

static inline size_t align_up(size_t v, size_t a) { return (v + a - 1) & ~(a - 1); }

// ---------- GEMM: h = x @ W ----------
// 256 threads = 4 waves. Block stages a 64-row x-tile in LDS once; wave wv
// computes output cols [16wv, 16wv+16) -> acc[16]/thread, lane = row.
// 6252 waves total (~24/CU) vs round-5's 1563 (~6/CU, VALUBusy 10.6%).
// readfirstlane forces wave id into SGPR so W loads stay scalar (s_load).
__global__ __launch_bounds__(256, 8) void gemm_block(
    const float* __restrict__ x, const float* __restrict__ w,
    float* __restrict__ h, int nrows) {
  __shared__ float xt[64 * PADF];
  const int tid = threadIdx.x;
  const int lane = tid & 63;
  const int wv = __builtin_amdgcn_readfirstlane(tid >> 6);  // 0..3, SGPR
  const int rb = blockIdx.x * 64;

  float acc[16];
#pragma unroll
  for (int c = 0; c < 16; ++c) acc[c] = 0.f;

  const int r = tid >> 3;           // 0..31: staging row
  const int kq = (tid & 7) << 2;    // 0,4,..,28: staging k-quad
  const float* wbase = w + wv * 16;

#pragma unroll 1
  for (int kc = 0; kc < IN_DIM; kc += 32) {
    // stage x[rb..rb+63][kc..kc+31]: 256 threads x 2 float4, coalesced
#pragma unroll
    for (int p = 0; p < 2; ++p) {
      int row = rb + r + p * 32;
      float4 v = (row < nrows)
                     ? *reinterpret_cast<const float4*>(x + (size_t)row * IN_DIM + kc + kq)
                     : make_float4(0.f, 0.f, 0.f, 0.f);
      *reinterpret_cast<float4*>(&xt[(r + p * 32) * PADF + kq]) = v;
    }
    __syncthreads();
#pragma unroll
    for (int k4 = 0; k4 < 32; k4 += 4) {
      float4 xv = *reinterpret_cast<const float4*>(&xt[lane * PADF + k4]);
#pragma unroll
      for (int kk = 0; kk < 4; ++kk) {
        float xs = (&xv.x)[kk];
        const float* wk = wbase + (size_t)(kc + k4 + kk) * OUT_DIM;  // uniform -> s_load
#pragma unroll
        for (int c = 0; c < 16; ++c)
          acc[c] = fmaf(xs, wk[c], acc[c]);
      }
    }
    __syncthreads();
  }

  int row = rb + lane;
  if (row < nrows) {
    // wave wv writes cols [16wv,16wv+16) of its 64 rows: one full 64B line/row
    float4* hp = reinterpret_cast<float4*>(h + (size_t)row * OUT_DIM + wv * 16);
#pragma unroll
    for (int c4 = 0; c4 < 4; ++c4)
      hp[c4] = make_float4(acc[c4 * 4], acc[c4 * 4 + 1], acc[c4 * 4 + 2], acc[c4 * 4 + 3]);
  }
}

// ---------- CSR build ----------

__global__ __launch_bounds__(256) void zero_i32(int* __restrict__ p, int n) {
  int tid = blockIdx.x * blockDim.x + threadIdx.x;
  int stride = gridDim.x * blockDim.x;
  for (int i = tid; i < n; i += stride) p[i] = 0;
}

__global__ __launch_bounds__(256) void hist_kernel(
    const int* __restrict__ dst, int nedges, int* __restrict__ counts) {
  int tid = blockIdx.x * blockDim.x + threadIdx.x;
  int stride = gridDim.x * blockDim.x;
  for (int e = tid; e < nedges; e += stride) atomicAdd(&counts[dst[e]], 1);
}

__global__ __launch_bounds__(1024) void scan_block(
    const int* __restrict__ counts, int n, int* __restrict__ offsets,
    int* __restrict__ bsums) {
  __shared__ int buf[1024];
  int gid = blockIdx.x * 1024 + threadIdx.x;
  int v = (gid < n) ? counts[gid] : 0;
  buf[threadIdx.x] = v;
  __syncthreads();
  for (int d = 1; d < 1024; d <<= 1) {
    int t = (threadIdx.x >= d) ? buf[threadIdx.x - d] : 0;
    __syncthreads();
    buf[threadIdx.x] += t;
    __syncthreads();
  }
  if (gid < n) offsets[gid] = buf[threadIdx.x] - v;  // exclusive
  if (threadIdx.x == 1023) bsums[blockIdx.x] = buf[1023];
}

__global__ void scan_bsums(int* __restrict__ bsums, int nb) {
  if (threadIdx.x == 0 && blockIdx.x == 0) {
    int run = 0;
    for (int i = 0; i < nb; ++i) { int v = bsums[i]; bsums[i] = run; run += v; }
  }
}

__global__ __launch_bounds__(256) void add_bsums(
    int* __restrict__ offsets, const int* __restrict__ bsums, int n,
    int* __restrict__ cursor, int nnodes) {
  int tid = blockIdx.x * blockDim.x + threadIdx.x;
  int stride = gridDim.x * blockDim.x;
  for (int i = tid; i < n; i += stride) {
    int o = offsets[i] + bsums[i >> 10];
    offsets[i] = o;
    if (i < nnodes) cursor[i] = o;
  }
}

// XCD-range-partitioned fill (round-4: 154 MB writebacks for 12.8 MB payload
// without partitioning; round-5: fill left the top-5).
__global__ __launch_bounds__(256) void fill_part_kernel(
    const int* __restrict__ ei, const float* __restrict__ ew, int nedges,
    int* __restrict__ cursor, int2* __restrict__ csr, int nnodes) {
  const int range = blockIdx.x & 7;
  const int ngroups = gridDim.x >> 3;
  const int group = blockIdx.x >> 3;
  const int lo = (int)((size_t)range * nnodes / 8);
  const int hi = (int)((size_t)(range + 1) * nnodes / 8);
  int tid = group * blockDim.x + threadIdx.x;
  int stride = ngroups * blockDim.x;
  for (int e = tid; e < nedges; e += stride) {
    int d = ei[e];
    if (d >= lo && d < hi) {
      int s = ei[nedges + e];
      float wv = ew[e];
      int p = atomicAdd(&cursor[d], 1);
      csr[p] = make_int2(s, __float_as_int(wv));
    }
  }
}

// ---------- gather: out[dst] = bias + sum_e w_e * h[src_e] ----------
__global__ __launch_bounds__(256) void gather_kernel(
    const int* __restrict__ offsets, const int2* __restrict__ csr,
    const float* __restrict__ h, const float* __restrict__ bias,
    float* __restrict__ out, int nnodes) {
  const int lane = threadIdx.x & 63;
  const int wid = blockIdx.x * (blockDim.x >> 6) + (threadIdx.x >> 6);
  const int nw = gridDim.x * (blockDim.x >> 6);
  const float b = bias[lane];

  for (int node = wid; node < nnodes; node += nw) {
    int beg = offsets[node];
    int end = offsets[node + 1];
    float acc = 0.f;
    for (int eo = beg; eo < end; eo += 64) {
      int cnt = min(64, end - eo);
      int2 me = (lane < cnt) ? csr[eo + lane] : make_int2(0, 0);
      int ms = me.x;
      float mw = __int_as_float(me.y);
      for (int j = 0; j < cnt; j += 8) {
        int s0 = __shfl(ms, j + 0), s1 = __shfl(ms, j + 1);
        int s2 = __shfl(ms, j + 2), s3 = __shfl(ms, j + 3);
        int s4 = __shfl(ms, j + 4), s5 = __shfl(ms, j + 5);
        int s6 = __shfl(ms, j + 6), s7 = __shfl(ms, j + 7);
        float w0 = __shfl(mw, j + 0), w1 = __shfl(mw, j + 1);
        float w2 = __shfl(mw, j + 2), w3 = __shfl(mw, j + 3);
        float w4 = __shfl(mw, j + 4), w5 = __shfl(mw, j + 5);
        float w6 = __shfl(mw, j + 6), w7 = __shfl(mw, j + 7);
        float h0 = h[(size_t)s0 * OUT_DIM + lane];
        float h1 = h[(size_t)s1 * OUT_DIM + lane];
        float h2 = h[(size_t)s2 * OUT_DIM + lane];
        float h3 = h[(size_t)s3 * OUT_DIM + lane];
        float h4 = h[(size_t)s4 * OUT_DIM + lane];
        float h5 = h[(size_t)s5 * OUT_DIM + lane];
        float h6 = h[(size_t)s6 * OUT_DIM + lane];
        float h7 = h[(size_t)s7 * OUT_DIM + lane];
        acc = fmaf(w0, h0, acc);
        acc = fmaf(w1, h1, acc);
        acc = fmaf(w2, h2, acc);
        acc = fmaf(w3, h3, acc);
        acc = fmaf(w4, h4, acc);
        acc = fmaf(w5, h5, acc);
        acc = fmaf(w6, h6, acc);
        acc = fmaf(w7, h7, acc);
      }
    }
    out[(size_t)node * OUT_DIM + lane] = acc + b;
  }
}

extern "C" void kernel_launch(void* const* d_in, const int* in_sizes, int n_in,
                              void* d_out, int out_size, void* d_ws, size_t ws_size,
                              hipStream_t stream) {
  const float* x    = (const float*)d_in[0];
  const int*   ei   = (const int*)d_in[1];    // [2, E]: row0 = dst, row1 = src
  const float* ew   = (const float*)d_in[2];
  const float* w    = (const float*)d_in[3];
  const float* bias = (const float*)d_in[4];
  float* out = (float*)d_out;

  const int nrows  = in_sizes[0] / IN_DIM;  // 100000
  const int nedges = in_sizes[2];           // 1600000
  const int nscan  = nrows + 1;
  const int nblk   = (nscan + 1023) / 1024;

  // ws layout
  char* ws = (char*)d_ws;
  size_t o = 0;
  float* h = (float*)(ws + o);           o += align_up((size_t)nrows * OUT_DIM * 4, 512);
  int* counts  = (int*)(ws + o);         o += align_up((size_t)nscan * 4, 512);
  int* offsets = (int*)(ws + o);         o += align_up((size_t)nscan * 4, 512);
  int* cursor  = (int*)(ws + o);         o += align_up((size_t)nrows * 4, 512);
  int* bsums   = (int*)(ws + o);         o += align_up((size_t)nblk * 4, 512);
  int2* csr    = (int2*)(ws + o);        o += align_up((size_t)nedges * 8, 512);

  hipLaunchKernelGGL(gemm_block, dim3((nrows + 63) / 64), dim3(256), 0, stream,
                     x, w, h, nrows);
  hipLaunchKernelGGL(zero_i32, dim3(128), dim3(256), 0, stream, counts, nscan);
  hipLaunchKernelGGL(hist_kernel, dim3(2048), dim3(256), 0, stream,
                     ei, nedges, counts);
  hipLaunchKernelGGL(scan_block, dim3(nblk), dim3(1024), 0, stream,
                     counts, nscan, offsets, bsums);
  hipLaunchKernelGGL(scan_bsums, dim3(1), dim3(64), 0, stream, bsums, nblk);
  hipLaunchKernelGGL(add_bsums, dim3(128), dim3(256), 0, stream,
                     offsets, bsums, nscan, cursor, nrows);
  hipLaunchKernelGGL(fill_part_kernel, dim3(2048), dim3(256), 0, stream,
                     ei, ew, nedges, cursor, csr, nrows);
  hipLaunchKernelGGL(gather_kernel, dim3(8192), dim3(256), 0, stream,
                     offsets, csr, h, bias, out, nrows);
}